// Round 2
// baseline (2493.656 us; speedup 1.0000x reference)
//
#include <hip/hip_runtime.h>
#include <math.h>

// Problem constants (fixed by reference)
#define S_LEN    1024
#define NHEAD    16
#define DHEAD    128
#define HIDDEN   2048
#define BATCH    2
#define BH       32            // BATCH*NHEAD
#define CACHE_B  204           // heavy+recent budget
#define RECENT_B 102
#define QK_SCALE 0.08838834764831845f   // 1/sqrt(128)

// ---------------------------------------------------------------------------
// Tiled fp32 GEMM, 128x128 tile, 256 threads, 8x8 per thread.
// MODE 0: C = hs @ {wq|wk|wv} (blockIdx.z selects), epilogue scatters to
//         [B,H,S,D] layout. MODE 1: plain row-major C = A @ B0.
// ---------------------------------------------------------------------------
template <int MODE>
__global__ __launch_bounds__(256) void gemm_f32(
    const float* __restrict__ A, const float* __restrict__ B0,
    const float* __restrict__ B1, const float* __restrict__ B2,
    float* __restrict__ C0, float* __restrict__ C1, float* __restrict__ C2) {
  __shared__ float As[16][136];
  __shared__ float Bs[16][136];
  const float* Bm;
  float* C;
  if (MODE == 0) {
    int z = blockIdx.z;
    Bm = (z == 0) ? B0 : ((z == 1) ? B1 : B2);
    C = (z == 0) ? C0 : ((z == 1) ? C1 : C2);
  } else {
    Bm = B0;
    C = C0;
  }
  const int tid = threadIdx.x;
  const int tx = tid & 15, ty = tid >> 4;
  const int m0 = blockIdx.y * 128, n0 = blockIdx.x * 128;

  float acc[8][8];
#pragma unroll
  for (int i = 0; i < 8; ++i)
#pragma unroll
    for (int j = 0; j < 8; ++j) acc[i][j] = 0.0f;

  for (int k0 = 0; k0 < HIDDEN; k0 += 16) {
#pragma unroll
    for (int l = 0; l < 2; ++l) {
      int f = tid + l * 256;
      int r = f >> 2, c = (f & 3) * 4;
      const float4 a =
          *(const float4*)&A[(size_t)(m0 + r) * HIDDEN + k0 + c];
      As[c + 0][r] = a.x;
      As[c + 1][r] = a.y;
      As[c + 2][r] = a.z;
      As[c + 3][r] = a.w;
    }
#pragma unroll
    for (int l = 0; l < 2; ++l) {
      int f = tid + l * 256;
      int r = f >> 5, c = (f & 31) * 4;
      *(float4*)&Bs[r][c] =
          *(const float4*)&Bm[(size_t)(k0 + r) * HIDDEN + n0 + c];
    }
    __syncthreads();
#pragma unroll
    for (int kk = 0; kk < 16; ++kk) {
      float av[8], bv[8];
      *(float4*)&av[0] = *(float4*)&As[kk][ty * 8];
      *(float4*)&av[4] = *(float4*)&As[kk][ty * 8 + 4];
      *(float4*)&bv[0] = *(float4*)&Bs[kk][tx * 8];
      *(float4*)&bv[4] = *(float4*)&Bs[kk][tx * 8 + 4];
#pragma unroll
      for (int i = 0; i < 8; ++i)
#pragma unroll
        for (int j = 0; j < 8; ++j) acc[i][j] += av[i] * bv[j];
    }
    __syncthreads();
  }

#pragma unroll
  for (int i = 0; i < 8; ++i) {
    int m = m0 + ty * 8 + i;
#pragma unroll
    for (int j = 0; j < 8; ++j) {
      int n = n0 + tx * 8 + j;
      if (MODE == 0) {
        int b = m >> 10, s = m & (S_LEN - 1);
        int h = n >> 7, d = n & (DHEAD - 1);
        C[(((size_t)(b * NHEAD + h) * S_LEN + s) * DHEAD) + d] = acc[i][j];
      } else {
        C[(size_t)m * HIDDEN + n] = acc[i][j];
      }
    }
  }
}

// ---------------------------------------------------------------------------
// RoPE in place on Q,K ([BH,S,D] layout).
// ---------------------------------------------------------------------------
__global__ __launch_bounds__(256) void rope_qk(float* __restrict__ Q,
                                               float* __restrict__ K) {
  int g = blockIdx.x * 4 + (threadIdx.x >> 6);  // row id over BH*S
  int lane = threadIdx.x & 63;
  int s = g & (S_LEN - 1);
  double invf = exp(-((double)(2 * lane) / 128.0) * log(10000.0));
  float angle = (float)s * (float)invf;
  float c = (float)cos((double)angle);
  float sn = (float)sin((double)angle);
  size_t base = (size_t)g * DHEAD;
  float q0 = Q[base + lane], q1 = Q[base + lane + 64];
  Q[base + lane] = q0 * c - q1 * sn;
  Q[base + lane + 64] = q1 * c + q0 * sn;
  float k0 = K[base + lane], k1 = K[base + lane + 64];
  K[base + lane] = k0 * c - k1 * sn;
  K[base + lane + 64] = k1 * c + k0 * sn;
}

// ---------------------------------------------------------------------------
// Per (b,h): mean |k| over first 204 roped tokens, stable argsort rank,
// keep top-6 dims; pack Qp/Kp[bh][s][0..5] (stride 8).
// ---------------------------------------------------------------------------
__global__ __launch_bounds__(128) void keep_pack(
    const float* __restrict__ Q, const float* __restrict__ K,
    float* __restrict__ Qp, float* __restrict__ Kp) {
  int bh = blockIdx.x;
  int d = threadIdx.x;
  __shared__ float ma[128];
  __shared__ int kf[128];
  __shared__ int kidx[8];
  const float* Kb = K + (size_t)bh * S_LEN * DHEAD;
  const float* Qb = Q + (size_t)bh * S_LEN * DHEAD;
  float sum = 0.0f;
  for (int s = 0; s < CACHE_B; ++s) sum += fabsf(Kb[(size_t)s * DHEAD + d]);
  ma[d] = sum / 204.0f;
  __syncthreads();
  float v = ma[d];
  int rank = 0;
  for (int e = 0; e < 128; ++e) {
    float u = ma[e];
    rank += (u < v) || (u == v && e < d);  // stable-argsort rank
  }
  int keep = (rank >= 128 - 6);
  kf[d] = keep;
  __syncthreads();
  if (keep) {
    int pos = 0;
    for (int e = 0; e < d; ++e) pos += kf[e];
    kidx[pos] = d;
  }
  __syncthreads();
  int i0 = kidx[0], i1 = kidx[1], i2 = kidx[2];
  int i3 = kidx[3], i4 = kidx[4], i5 = kidx[5];
  for (int s = threadIdx.x; s < S_LEN; s += 128) {
    size_t src = (size_t)s * DHEAD;
    size_t dst = ((size_t)bh * S_LEN + s) * 8;
    Qp[dst + 0] = Qb[src + i0]; Qp[dst + 1] = Qb[src + i1];
    Qp[dst + 2] = Qb[src + i2]; Qp[dst + 3] = Qb[src + i3];
    Qp[dst + 4] = Qb[src + i4]; Qp[dst + 5] = Qb[src + i5];
    Kp[dst + 0] = Kb[src + i0]; Kp[dst + 1] = Kb[src + i1];
    Kp[dst + 2] = Kb[src + i2]; Kp[dst + 3] = Kb[src + i3];
    Kp[dst + 4] = Kb[src + i4]; Kp[dst + 5] = Kb[src + i5];
  }
}

// ---------------------------------------------------------------------------
// Batched A_full[bh][t][s] = QK_SCALE * Q[t]·K[s], lower-triangular tiles only.
// ---------------------------------------------------------------------------
__global__ __launch_bounds__(256) void qkt_scores(
    const float* __restrict__ Q, const float* __restrict__ K,
    float* __restrict__ Af) {
  if (blockIdx.x > blockIdx.y) return;  // strictly-upper tiles never read
  __shared__ float Qs[16][136];
  __shared__ float Ks[16][136];
  const int bh = blockIdx.z;
  const int tid = threadIdx.x;
  const int tx = tid & 15, ty = tid >> 4;
  const int m0 = blockIdx.y * 128, n0 = blockIdx.x * 128;
  const float* Qb = Q + (size_t)bh * S_LEN * DHEAD;
  const float* Kb = K + (size_t)bh * S_LEN * DHEAD;
  float acc[8][8];
#pragma unroll
  for (int i = 0; i < 8; ++i)
#pragma unroll
    for (int j = 0; j < 8; ++j) acc[i][j] = 0.0f;

  for (int k0 = 0; k0 < DHEAD; k0 += 16) {
#pragma unroll
    for (int l = 0; l < 2; ++l) {
      int f = tid + l * 256;
      int r = f >> 2, c = (f & 3) * 4;
      const float4 q = *(const float4*)&Qb[(size_t)(m0 + r) * DHEAD + k0 + c];
      Qs[c + 0][r] = q.x; Qs[c + 1][r] = q.y;
      Qs[c + 2][r] = q.z; Qs[c + 3][r] = q.w;
      const float4 kv = *(const float4*)&Kb[(size_t)(n0 + r) * DHEAD + k0 + c];
      Ks[c + 0][r] = kv.x; Ks[c + 1][r] = kv.y;
      Ks[c + 2][r] = kv.z; Ks[c + 3][r] = kv.w;
    }
    __syncthreads();
#pragma unroll
    for (int kk = 0; kk < 16; ++kk) {
      float av[8], bv[8];
      *(float4*)&av[0] = *(float4*)&Qs[kk][ty * 8];
      *(float4*)&av[4] = *(float4*)&Qs[kk][ty * 8 + 4];
      *(float4*)&bv[0] = *(float4*)&Ks[kk][tx * 8];
      *(float4*)&bv[4] = *(float4*)&Ks[kk][tx * 8 + 4];
#pragma unroll
      for (int i = 0; i < 8; ++i)
#pragma unroll
        for (int j = 0; j < 8; ++j) acc[i][j] += av[i] * bv[j];
    }
    __syncthreads();
  }
  float* Cb = Af + (size_t)bh * S_LEN * S_LEN;
#pragma unroll
  for (int i = 0; i < 8; ++i) {
    int t = m0 + ty * 8 + i;
#pragma unroll
    for (int j = 0; j < 8; ++j) {
      int s = n0 + tx * 8 + j;
      Cb[(size_t)t * S_LEN + s] = acc[i][j] * QK_SCALE;
    }
  }
}

// ---------------------------------------------------------------------------
// Sequential H2O eviction scan — single wave per (b,h), barrier-free.
// Lane owns s = lane*16 .. lane*16+15 (coalesced float4 loads, eviction
// state in a 16-bit register mask). 4-row register ring buffer, loop
// unrolled x4 (static slot indices) so each row's loads are issued 4
// iterations before use -> L2/L3 latency hidden. Argmin over 64 lanes via
// 6-step shfl_xor butterfly, ties -> smallest s (matches jnp.argmin).
// ---------------------------------------------------------------------------
__global__ __launch_bounds__(64) void scan_evict(const float* __restrict__ Af,
                                                 int* __restrict__ evt) {
  const int bh = blockIdx.x;
  const int lane = threadIdx.x;
  const float* Ab = Af + (size_t)bh * S_LEN * S_LEN;
  const int sbase = lane * 16;
  unsigned evmask = 0;
#pragma unroll
  for (int i = 0; i < 16; ++i) evt[bh * S_LEN + sbase + i] = 0x7fffffff;

  float4 ring[4][4];
#pragma unroll
  for (int r = 0; r < 4; ++r)
#pragma unroll
    for (int j = 0; j < 4; ++j)
      ring[r][j] =
          *(const float4*)&Ab[(size_t)(204 + r) * S_LEN + sbase + j * 4];

  for (int tb = 205; tb <= 1023; tb += 4) {
#pragma unroll
    for (int u = 0; u < 4; ++u) {
      const int t = tb + u;
      const int limit = t - RECENT_B;
      float v = INFINITY;
      int idx = 0x7fffffff;
      // consume slot u = row t-1; ascending s with strict < keeps first-min
#pragma unroll
      for (int j = 0; j < 4; ++j) {
        const float4 f = ring[u][j];
        const float e[4] = {f.x, f.y, f.z, f.w};
#pragma unroll
        for (int q = 0; q < 4; ++q) {
          const int bit = j * 4 + q;
          const int s = sbase + bit;
          const bool ok = (s < limit) && !((evmask >> bit) & 1u);
          if (ok && e[q] < v) { v = e[q]; idx = s; }
        }
      }
      // prefetch row t+3 into slot u (consumed at iteration t+4)
      const int pr = (t + 3 <= 1023) ? (t + 3) : 1023;
#pragma unroll
      for (int j = 0; j < 4; ++j)
        ring[u][j] = *(const float4*)&Ab[(size_t)pr * S_LEN + sbase + j * 4];
      // 64-lane argmin butterfly
#pragma unroll
      for (int off = 32; off; off >>= 1) {
        const float vo = __shfl_xor(v, off, 64);
        const int io = __shfl_xor(idx, off, 64);
        if (vo < v || (vo == v && io < idx)) { v = vo; idx = io; }
      }
      if (t <= 1023) {
        if ((idx >> 4) == lane) evmask |= (1u << (idx & 15));
        if (lane == 0) evt[bh * S_LEN + idx] = t;
      }
    }
  }
}

// ---------------------------------------------------------------------------
// Final attention: 8 query rows per workgroup. Phase 1 (wave per 2 rows):
// score = evicted(s by time t) ? QK_SCALE*dot6(Qp,Kp) : A_full[t][s];
// softmax -> P in LDS + 1/sum. Phase 2: out = (P·V)/sum -> [B,S,HID].
// ---------------------------------------------------------------------------
__global__ __launch_bounds__(256) void attn_av(
    const float* __restrict__ Af, const float* __restrict__ Qp,
    const float* __restrict__ Kp, const int* __restrict__ evt,
    const float* __restrict__ V, float* __restrict__ AO) {
  const int t0 = blockIdx.x * 8;
  const int bh = blockIdx.y;
  __shared__ float P[8][S_LEN];
  __shared__ float rinv[8];
  const int tid = threadIdx.x;
  const int lane = tid & 63, wave = tid >> 6;
  const float* Ab = Af + (size_t)bh * S_LEN * S_LEN;
  const int* eb = evt + bh * S_LEN;
  const float* Kpb = Kp + (size_t)bh * S_LEN * 8;

  for (int rr = 0; rr < 2; ++rr) {
    const int r = wave * 2 + rr;
    const int t = t0 + r;
    float qp[6];
#pragma unroll
    for (int j = 0; j < 6; ++j) qp[j] = Qp[((size_t)bh * S_LEN + t) * 8 + j];
    float vals[16];
    float m = -INFINITY;
#pragma unroll
    for (int i = 0; i < 16; ++i) {
      int s = lane + i * 64;
      float sc = 0.0f;
      if (s <= t) {
        if (eb[s] <= t) {
          const float* kr = &Kpb[(size_t)s * 8];
          sc = QK_SCALE * (qp[0] * kr[0] + qp[1] * kr[1] + qp[2] * kr[2] +
                           qp[3] * kr[3] + qp[4] * kr[4] + qp[5] * kr[5]);
        } else {
          sc = Ab[(size_t)t * S_LEN + s];
        }
        m = fmaxf(m, sc);
      }
      vals[i] = sc;
    }
    for (int off = 32; off; off >>= 1) m = fmaxf(m, __shfl_xor(m, off, 64));
    float sum = 0.0f;
#pragma unroll
    for (int i = 0; i < 16; ++i) {
      int s = lane + i * 64;
      float p = 0.0f;
      if (s <= t) {
        p = expf(vals[i] - m);
        sum += p;
      }
      P[r][s] = p;
    }
    for (int off = 32; off; off >>= 1) sum += __shfl_xor(sum, off, 64);
    if (lane == 0) rinv[r] = 1.0f / sum;
  }
  __syncthreads();

  const int d4 = (tid & 31) * 4;
  const int r = tid >> 5;
  const int t = t0 + r;
  const float* Vb = V + (size_t)bh * S_LEN * DHEAD;
  float ax = 0.f, ay = 0.f, az = 0.f, aw = 0.f;
  const int smax = t0 + 7;
  for (int s = 0; s <= smax; ++s) {
    float p = P[r][s];
    const float4 vv = *(const float4*)&Vb[(size_t)s * DHEAD + d4];
    ax += p * vv.x; ay += p * vv.y; az += p * vv.z; aw += p * vv.w;
  }
  const float ri = rinv[r];
  const int b = bh >> 4, h = bh & 15;
  float4 o;
  o.x = ax * ri; o.y = ay * ri; o.z = az * ri; o.w = aw * ri;
  *(float4*)&AO[((size_t)(b * S_LEN + t)) * HIDDEN + h * DHEAD + d4] = o;
}

// ---------------------------------------------------------------------------
extern "C" void kernel_launch(void* const* d_in, const int* in_sizes, int n_in,
                              void* d_out, int out_size, void* d_ws,
                              size_t ws_size, hipStream_t stream) {
  const float* hs = (const float*)d_in[0];
  const float* wq = (const float*)d_in[1];
  const float* wk = (const float*)d_in[2];
  const float* wv = (const float*)d_in[3];
  const float* wo = (const float*)d_in[4];
  float* out = (float*)d_out;

  const size_t SZ_QKV = (size_t)BH * S_LEN * DHEAD;
  float* Q = (float*)d_ws;
  float* K = Q + SZ_QKV;
  float* V = K + SZ_QKV;
  float* Af = V + SZ_QKV;
  float* Qp = Af + (size_t)BH * S_LEN * S_LEN;
  float* Kp = Qp + (size_t)BH * S_LEN * 8;
  int* evt = (int*)(Kp + (size_t)BH * S_LEN * 8);
  float* AO = (float*)(evt + BH * S_LEN);

  gemm_f32<0><<<dim3(16, 16, 3), 256, 0, stream>>>(hs, wq, wk, wv, Q, K, V);
  rope_qk<<<dim3(BH * S_LEN / 4), 256, 0, stream>>>(Q, K);
  keep_pack<<<dim3(BH), 128, 0, stream>>>(Q, K, Qp, Kp);
  qkt_scores<<<dim3(8, 8, BH), 256, 0, stream>>>(Q, K, Af);
  scan_evict<<<dim3(BH), 64, 0, stream>>>(Af, evt);
  attn_av<<<dim3(S_LEN / 8, BH), 256, 0, stream>>>(Af, Qp, Kp, evt, V, AO);
  gemm_f32<1><<<dim3(16, 16, 1), 256, 0, stream>>>(AO, wo, nullptr, nullptr,
                                                   out, nullptr, nullptr);
}

// Round 3
// 2110.036 us; speedup vs baseline: 1.1818x; 1.1818x over previous
//
#include <hip/hip_runtime.h>
#include <math.h>

// Problem constants (fixed by reference)
#define S_LEN    1024
#define NHEAD    16
#define DHEAD    128
#define HIDDEN   2048
#define BATCH    2
#define BH       32            // BATCH*NHEAD
#define CACHE_B  204           // heavy+recent budget
#define RECENT_B 102
#define QK_SCALE 0.08838834764831845f   // 1/sqrt(128)

// ---------------------------------------------------------------------------
// Tiled fp32 GEMM, 128x128 tile, 256 threads, 8x8 per thread.
// MODE 0: C = hs @ {wq|wk|wv} (blockIdx.z selects), epilogue scatters to
//         [B,H,S,D] layout. MODE 1: plain row-major C = A @ B0.
// ---------------------------------------------------------------------------
template <int MODE>
__global__ __launch_bounds__(256) void gemm_f32(
    const float* __restrict__ A, const float* __restrict__ B0,
    const float* __restrict__ B1, const float* __restrict__ B2,
    float* __restrict__ C0, float* __restrict__ C1, float* __restrict__ C2) {
  __shared__ float As[16][136];
  __shared__ float Bs[16][136];
  const float* Bm;
  float* C;
  if (MODE == 0) {
    int z = blockIdx.z;
    Bm = (z == 0) ? B0 : ((z == 1) ? B1 : B2);
    C = (z == 0) ? C0 : ((z == 1) ? C1 : C2);
  } else {
    Bm = B0;
    C = C0;
  }
  const int tid = threadIdx.x;
  const int tx = tid & 15, ty = tid >> 4;
  const int m0 = blockIdx.y * 128, n0 = blockIdx.x * 128;

  float acc[8][8];
#pragma unroll
  for (int i = 0; i < 8; ++i)
#pragma unroll
    for (int j = 0; j < 8; ++j) acc[i][j] = 0.0f;

  for (int k0 = 0; k0 < HIDDEN; k0 += 16) {
#pragma unroll
    for (int l = 0; l < 2; ++l) {
      int f = tid + l * 256;
      int r = f >> 2, c = (f & 3) * 4;
      const float4 a =
          *(const float4*)&A[(size_t)(m0 + r) * HIDDEN + k0 + c];
      As[c + 0][r] = a.x;
      As[c + 1][r] = a.y;
      As[c + 2][r] = a.z;
      As[c + 3][r] = a.w;
    }
#pragma unroll
    for (int l = 0; l < 2; ++l) {
      int f = tid + l * 256;
      int r = f >> 5, c = (f & 31) * 4;
      *(float4*)&Bs[r][c] =
          *(const float4*)&Bm[(size_t)(k0 + r) * HIDDEN + n0 + c];
    }
    __syncthreads();
#pragma unroll
    for (int kk = 0; kk < 16; ++kk) {
      float av[8], bv[8];
      *(float4*)&av[0] = *(float4*)&As[kk][ty * 8];
      *(float4*)&av[4] = *(float4*)&As[kk][ty * 8 + 4];
      *(float4*)&bv[0] = *(float4*)&Bs[kk][tx * 8];
      *(float4*)&bv[4] = *(float4*)&Bs[kk][tx * 8 + 4];
#pragma unroll
      for (int i = 0; i < 8; ++i)
#pragma unroll
        for (int j = 0; j < 8; ++j) acc[i][j] += av[i] * bv[j];
    }
    __syncthreads();
  }

#pragma unroll
  for (int i = 0; i < 8; ++i) {
    int m = m0 + ty * 8 + i;
#pragma unroll
    for (int j = 0; j < 8; ++j) {
      int n = n0 + tx * 8 + j;
      if (MODE == 0) {
        int b = m >> 10, s = m & (S_LEN - 1);
        int h = n >> 7, d = n & (DHEAD - 1);
        C[(((size_t)(b * NHEAD + h) * S_LEN + s) * DHEAD) + d] = acc[i][j];
      } else {
        C[(size_t)m * HIDDEN + n] = acc[i][j];
      }
    }
  }
}

// ---------------------------------------------------------------------------
// RoPE in place on Q,K ([BH,S,D] layout).
// ---------------------------------------------------------------------------
__global__ __launch_bounds__(256) void rope_qk(float* __restrict__ Q,
                                               float* __restrict__ K) {
  int g = blockIdx.x * 4 + (threadIdx.x >> 6);  // row id over BH*S
  int lane = threadIdx.x & 63;
  int s = g & (S_LEN - 1);
  double invf = exp(-((double)(2 * lane) / 128.0) * log(10000.0));
  float angle = (float)s * (float)invf;
  float c = (float)cos((double)angle);
  float sn = (float)sin((double)angle);
  size_t base = (size_t)g * DHEAD;
  float q0 = Q[base + lane], q1 = Q[base + lane + 64];
  Q[base + lane] = q0 * c - q1 * sn;
  Q[base + lane + 64] = q1 * c + q0 * sn;
  float k0 = K[base + lane], k1 = K[base + lane + 64];
  K[base + lane] = k0 * c - k1 * sn;
  K[base + lane + 64] = k1 * c + k0 * sn;
}

// ---------------------------------------------------------------------------
// Per (b,h): mean |k| over first 204 roped tokens, stable argsort rank,
// keep top-6 dims; pack Qp/Kp[bh][s][0..5] (stride 8).
// ---------------------------------------------------------------------------
__global__ __launch_bounds__(128) void keep_pack(
    const float* __restrict__ Q, const float* __restrict__ K,
    float* __restrict__ Qp, float* __restrict__ Kp) {
  int bh = blockIdx.x;
  int d = threadIdx.x;
  __shared__ float ma[128];
  __shared__ int kf[128];
  __shared__ int kidx[8];
  const float* Kb = K + (size_t)bh * S_LEN * DHEAD;
  const float* Qb = Q + (size_t)bh * S_LEN * DHEAD;
  float sum = 0.0f;
  for (int s = 0; s < CACHE_B; ++s) sum += fabsf(Kb[(size_t)s * DHEAD + d]);
  ma[d] = sum / 204.0f;
  __syncthreads();
  float v = ma[d];
  int rank = 0;
  for (int e = 0; e < 128; ++e) {
    float u = ma[e];
    rank += (u < v) || (u == v && e < d);  // stable-argsort rank
  }
  int keep = (rank >= 128 - 6);
  kf[d] = keep;
  __syncthreads();
  if (keep) {
    int pos = 0;
    for (int e = 0; e < d; ++e) pos += kf[e];
    kidx[pos] = d;
  }
  __syncthreads();
  int i0 = kidx[0], i1 = kidx[1], i2 = kidx[2];
  int i3 = kidx[3], i4 = kidx[4], i5 = kidx[5];
  for (int s = threadIdx.x; s < S_LEN; s += 128) {
    size_t src = (size_t)s * DHEAD;
    size_t dst = ((size_t)bh * S_LEN + s) * 8;
    Qp[dst + 0] = Qb[src + i0]; Qp[dst + 1] = Qb[src + i1];
    Qp[dst + 2] = Qb[src + i2]; Qp[dst + 3] = Qb[src + i3];
    Qp[dst + 4] = Qb[src + i4]; Qp[dst + 5] = Qb[src + i5];
    Kp[dst + 0] = Kb[src + i0]; Kp[dst + 1] = Kb[src + i1];
    Kp[dst + 2] = Kb[src + i2]; Kp[dst + 3] = Kb[src + i3];
    Kp[dst + 4] = Kb[src + i4]; Kp[dst + 5] = Kb[src + i5];
  }
}

// ---------------------------------------------------------------------------
// Batched A_full[bh][t][s] = QK_SCALE * Q[t]·K[s], lower-triangular tiles only.
// ---------------------------------------------------------------------------
__global__ __launch_bounds__(256) void qkt_scores(
    const float* __restrict__ Q, const float* __restrict__ K,
    float* __restrict__ Af) {
  if (blockIdx.x > blockIdx.y) return;  // strictly-upper tiles never read
  __shared__ float Qs[16][136];
  __shared__ float Ks[16][136];
  const int bh = blockIdx.z;
  const int tid = threadIdx.x;
  const int tx = tid & 15, ty = tid >> 4;
  const int m0 = blockIdx.y * 128, n0 = blockIdx.x * 128;
  const float* Qb = Q + (size_t)bh * S_LEN * DHEAD;
  const float* Kb = K + (size_t)bh * S_LEN * DHEAD;
  float acc[8][8];
#pragma unroll
  for (int i = 0; i < 8; ++i)
#pragma unroll
    for (int j = 0; j < 8; ++j) acc[i][j] = 0.0f;

  for (int k0 = 0; k0 < DHEAD; k0 += 16) {
#pragma unroll
    for (int l = 0; l < 2; ++l) {
      int f = tid + l * 256;
      int r = f >> 2, c = (f & 3) * 4;
      const float4 q = *(const float4*)&Qb[(size_t)(m0 + r) * DHEAD + k0 + c];
      Qs[c + 0][r] = q.x; Qs[c + 1][r] = q.y;
      Qs[c + 2][r] = q.z; Qs[c + 3][r] = q.w;
      const float4 kv = *(const float4*)&Kb[(size_t)(n0 + r) * DHEAD + k0 + c];
      Ks[c + 0][r] = kv.x; Ks[c + 1][r] = kv.y;
      Ks[c + 2][r] = kv.z; Ks[c + 3][r] = kv.w;
    }
    __syncthreads();
#pragma unroll
    for (int kk = 0; kk < 16; ++kk) {
      float av[8], bv[8];
      *(float4*)&av[0] = *(float4*)&Qs[kk][ty * 8];
      *(float4*)&av[4] = *(float4*)&Qs[kk][ty * 8 + 4];
      *(float4*)&bv[0] = *(float4*)&Ks[kk][tx * 8];
      *(float4*)&bv[4] = *(float4*)&Ks[kk][tx * 8 + 4];
#pragma unroll
      for (int i = 0; i < 8; ++i)
#pragma unroll
        for (int j = 0; j < 8; ++j) acc[i][j] += av[i] * bv[j];
    }
    __syncthreads();
  }
  float* Cb = Af + (size_t)bh * S_LEN * S_LEN;
#pragma unroll
  for (int i = 0; i < 8; ++i) {
    int t = m0 + ty * 8 + i;
#pragma unroll
    for (int j = 0; j < 8; ++j) {
      int s = n0 + tx * 8 + j;
      Cb[(size_t)t * S_LEN + s] = acc[i][j] * QK_SCALE;
    }
  }
}

// ---------------------------------------------------------------------------
// Sequential H2O eviction scan — single wave per (b,h), barrier-free.
// Lane owns s = lane*16..lane*16+15. 8-row register ring; each row's base
// pointer is laundered through an empty asm so the compiler cannot CSE/sink
// the prefetch loads to their consume point (round-2 failure mode: VGPR=48
// proved the ring was collapsed, exposing full memory latency every step).
// Reduce: sortable-uint key packed with index -> single u64 min, exact
// first-index tie-break (matches jnp.argmin). Tree depth 4 in lane + 6-stage
// 64-lane butterfly.
// ---------------------------------------------------------------------------
__device__ __forceinline__ const float4* opq(const float4* p) {
  asm volatile("" : "+v"(p));
  return p;
}

__global__ __launch_bounds__(64, 1) void scan_evict(
    const float* __restrict__ Af, int* __restrict__ evt) {
  const int bh = blockIdx.x;
  const int lane = threadIdx.x;
  const float4* Ab4 = (const float4*)(Af + (size_t)bh * S_LEN * S_LEN);
  const int sbase = lane * 16;
  unsigned evmask = 0;
#pragma unroll
  for (int i = 0; i < 16; ++i) evt[bh * S_LEN + sbase + i] = 0x7fffffff;

  // ring[r][j]: row (t-1 + r) mod 8 of A, this lane's 16 floats
  float4 ring[8][4];
#pragma unroll
  for (int r = 0; r < 8; ++r) {
    const float4* rp = opq(Ab4 + (size_t)(204 + r) * 256 + lane * 4);
#pragma unroll
    for (int j = 0; j < 4; ++j) ring[r][j] = rp[j];
  }

  for (int tb = 205; tb <= 1023; tb += 8) {
#pragma unroll
    for (int u = 0; u < 8; ++u) {
      const int t = tb + u;
      if (t > 1023) break;
      const int limit = t - RECENT_B;
      // per-lane eligibility mask over 16 owned slots
      const int dlt = limit - sbase;
      unsigned wm = (dlt <= 0) ? 0u
                               : ((dlt >= 16) ? 0xffffu : ((1u << dlt) - 1u));
      const unsigned elig = wm & ~evmask;
      // build 16 u64 keys: (sortable_uint(score) << 32) | s ; ineligible -> MAX
      unsigned long long k[16];
#pragma unroll
      for (int j = 0; j < 4; ++j) {
        const float4 f = ring[u][j];
        const float e[4] = {f.x, f.y, f.z, f.w};
#pragma unroll
        for (int q = 0; q < 4; ++q) {
          const int bit = j * 4 + q;
          unsigned su = __float_as_uint(e[q]);
          su ^= (unsigned)((int)su >> 31) | 0x80000000u;
          const bool ok = (elig >> bit) & 1u;
          k[bit] = ok ? (((unsigned long long)su << 32) |
                         (unsigned)(sbase + bit))
                      : ~0ull;
        }
      }
      // prefetch row t+7 into slot u (consumed 8 steps later)
      const int pr = (t + 7 <= 1023) ? (t + 7) : 1023;
      {
        const float4* rp = opq(Ab4 + (size_t)pr * 256 + lane * 4);
#pragma unroll
        for (int j = 0; j < 4; ++j) ring[u][j] = rp[j];
      }
      // in-lane tree min (depth 4)
#pragma unroll
      for (int st = 8; st; st >>= 1)
#pragma unroll
        for (int i = 0; i < 16; ++i)
          if (i < st && k[i + st] < k[i]) k[i] = k[i + st];
      unsigned long long key = k[0];
      // 64-lane butterfly
#pragma unroll
      for (int off = 32; off; off >>= 1) {
        const unsigned long long ko = __shfl_xor(key, off, 64);
        if (ko < key) key = ko;
      }
      const int idx = (int)(unsigned)key;  // low 32 bits = s
      if ((idx >> 4) == lane) evmask |= (1u << (idx & 15));
      if (lane == 0) evt[bh * S_LEN + idx] = t;
    }
  }
}

// ---------------------------------------------------------------------------
// Final attention: 8 query rows per workgroup. Phase 1 (wave per 2 rows):
// score = evicted(s by time t) ? QK_SCALE*dot6(Qp,Kp) : A_full[t][s];
// softmax -> P in LDS + 1/sum. Phase 2: out = (P·V)/sum -> [B,S,HID],
// P read as float4 (4 s per LDS op).
// ---------------------------------------------------------------------------
__global__ __launch_bounds__(256) void attn_av(
    const float* __restrict__ Af, const float* __restrict__ Qp,
    const float* __restrict__ Kp, const int* __restrict__ evt,
    const float* __restrict__ V, float* __restrict__ AO) {
  const int t0 = blockIdx.x * 8;
  const int bh = blockIdx.y;
  __shared__ float P[8][S_LEN];
  __shared__ float rinv[8];
  const int tid = threadIdx.x;
  const int lane = tid & 63, wave = tid >> 6;
  const float* Ab = Af + (size_t)bh * S_LEN * S_LEN;
  const int* eb = evt + bh * S_LEN;
  const float* Kpb = Kp + (size_t)bh * S_LEN * 8;

  for (int rr = 0; rr < 2; ++rr) {
    const int r = wave * 2 + rr;
    const int t = t0 + r;
    float qp[6];
#pragma unroll
    for (int j = 0; j < 6; ++j) qp[j] = Qp[((size_t)bh * S_LEN + t) * 8 + j];
    float vals[16];
    float m = -INFINITY;
#pragma unroll
    for (int i = 0; i < 16; ++i) {
      int s = lane + i * 64;
      float sc = 0.0f;
      if (s <= t) {
        if (eb[s] <= t) {
          const float* kr = &Kpb[(size_t)s * 8];
          sc = QK_SCALE * (qp[0] * kr[0] + qp[1] * kr[1] + qp[2] * kr[2] +
                           qp[3] * kr[3] + qp[4] * kr[4] + qp[5] * kr[5]);
        } else {
          sc = Ab[(size_t)t * S_LEN + s];
        }
        m = fmaxf(m, sc);
      }
      vals[i] = sc;
    }
    for (int off = 32; off; off >>= 1) m = fmaxf(m, __shfl_xor(m, off, 64));
    float sum = 0.0f;
#pragma unroll
    for (int i = 0; i < 16; ++i) {
      int s = lane + i * 64;
      float p = 0.0f;
      if (s <= t) {
        p = expf(vals[i] - m);
        sum += p;
      }
      P[r][s] = p;
    }
    for (int off = 32; off; off >>= 1) sum += __shfl_xor(sum, off, 64);
    if (lane == 0) rinv[r] = 1.0f / sum;
  }
  __syncthreads();

  const int d4 = (tid & 31) * 4;
  const int r = tid >> 5;
  const int t = t0 + r;
  const float* Vb = V + (size_t)bh * S_LEN * DHEAD;
  float ax = 0.f, ay = 0.f, az = 0.f, aw = 0.f;
  const int smax = t0 + 7;
  for (int s4 = 0; s4 <= smax; s4 += 4) {
    const float4 p4 = *(const float4*)&P[r][s4];
    const float4 v0 = *(const float4*)&Vb[(size_t)(s4 + 0) * DHEAD + d4];
    const float4 v1 = *(const float4*)&Vb[(size_t)(s4 + 1) * DHEAD + d4];
    const float4 v2 = *(const float4*)&Vb[(size_t)(s4 + 2) * DHEAD + d4];
    const float4 v3 = *(const float4*)&Vb[(size_t)(s4 + 3) * DHEAD + d4];
    ax += p4.x * v0.x + p4.y * v1.x + p4.z * v2.x + p4.w * v3.x;
    ay += p4.x * v0.y + p4.y * v1.y + p4.z * v2.y + p4.w * v3.y;
    az += p4.x * v0.z + p4.y * v1.z + p4.z * v2.z + p4.w * v3.z;
    aw += p4.x * v0.w + p4.y * v1.w + p4.z * v2.w + p4.w * v3.w;
  }
  const float ri = rinv[r];
  const int b = bh >> 4, h = bh & 15;
  float4 o;
  o.x = ax * ri; o.y = ay * ri; o.z = az * ri; o.w = aw * ri;
  *(float4*)&AO[((size_t)(b * S_LEN + t)) * HIDDEN + h * DHEAD + d4] = o;
}

// ---------------------------------------------------------------------------
extern "C" void kernel_launch(void* const* d_in, const int* in_sizes, int n_in,
                              void* d_out, int out_size, void* d_ws,
                              size_t ws_size, hipStream_t stream) {
  const float* hs = (const float*)d_in[0];
  const float* wq = (const float*)d_in[1];
  const float* wk = (const float*)d_in[2];
  const float* wv = (const float*)d_in[3];
  const float* wo = (const float*)d_in[4];
  float* out = (float*)d_out;

  const size_t SZ_QKV = (size_t)BH * S_LEN * DHEAD;
  float* Q = (float*)d_ws;
  float* K = Q + SZ_QKV;
  float* V = K + SZ_QKV;
  float* Af = V + SZ_QKV;
  float* Qp = Af + (size_t)BH * S_LEN * S_LEN;
  float* Kp = Qp + (size_t)BH * S_LEN * 8;
  int* evt = (int*)(Kp + (size_t)BH * S_LEN * 8);
  float* AO = (float*)(evt + BH * S_LEN);

  gemm_f32<0><<<dim3(16, 16, 3), 256, 0, stream>>>(hs, wq, wk, wv, Q, K, V);
  rope_qk<<<dim3(BH * S_LEN / 4), 256, 0, stream>>>(Q, K);
  keep_pack<<<dim3(BH), 128, 0, stream>>>(Q, K, Qp, Kp);
  qkt_scores<<<dim3(8, 8, BH), 256, 0, stream>>>(Q, K, Af);
  scan_evict<<<dim3(BH), 64, 0, stream>>>(Af, evt);
  attn_av<<<dim3(S_LEN / 8, BH), 256, 0, stream>>>(Af, Qp, Kp, evt, V, AO);
  gemm_f32<1><<<dim3(16, 16, 1), 256, 0, stream>>>(AO, wo, nullptr, nullptr,
                                                   out, nullptr, nullptr);
}